// Round 4
// baseline (714.451 us; speedup 1.0000x reference)
//
#include <hip/hip_runtime.h>

#define NT 8192
#define DD 1024
#define HH 4096
#define EE 8

typedef __attribute__((ext_vector_type(8))) short short8;
typedef __attribute__((ext_vector_type(4))) float f32x4;

__device__ __forceinline__ unsigned short f2bf(float f) {
    unsigned int u = __float_as_uint(f);
    u += 0x7FFFu + ((u >> 16) & 1u);   // round-to-nearest-even
    return (unsigned short)(u >> 16);
}

__device__ __forceinline__ void gload_lds16(const void* g, void* l) {
    __builtin_amdgcn_global_load_lds(
        (const __attribute__((address_space(1))) unsigned int*)g,
        (__attribute__((address_space(3))) unsigned int*)l, 16, 0, 0);
}

// pack 8 fp32 -> 8 bf16, one ds_write_b128
__device__ __forceinline__ void pack_store8(unsigned short* l, float4 a, float4 b) {
    uint4 w;
    w.x = (unsigned)f2bf(a.x) | ((unsigned)f2bf(a.y) << 16);
    w.y = (unsigned)f2bf(a.z) | ((unsigned)f2bf(a.w) << 16);
    w.z = (unsigned)f2bf(b.x) | ((unsigned)f2bf(b.y) << 16);
    w.w = (unsigned)f2bf(b.z) | ((unsigned)f2bf(b.w) << 16);
    *(uint4*)l = w;
}

// ---- router: one wave per token; argmax of x @ Wr^T + br ----
__global__ __launch_bounds__(256) void router_kernel(const float* __restrict__ x,
                                                     const float* __restrict__ Wr,
                                                     const float* __restrict__ br,
                                                     int* __restrict__ counts,
                                                     int* __restrict__ tlist) {
    __shared__ float sW[EE * DD];  // 32 KB
    const int t = threadIdx.x;
    for (int i = t; i < EE * DD / 4; i += 256)
        ((float4*)sW)[i] = ((const float4*)Wr)[i];
    __syncthreads();
    const int lane = t & 63;
    const int wv = t >> 6;
    const int token = blockIdx.x * 4 + wv;
    const float* xr = x + (size_t)token * DD;
    float acc[EE];
#pragma unroll
    for (int e = 0; e < EE; e++) acc[e] = 0.f;
    for (int k = lane; k < DD; k += 64) {
        float xv = xr[k];
#pragma unroll
        for (int e = 0; e < EE; e++) acc[e] += xv * sW[e * DD + k];
    }
#pragma unroll
    for (int off = 32; off > 0; off >>= 1) {
#pragma unroll
        for (int e = 0; e < EE; e++) acc[e] += __shfl_xor(acc[e], off);
    }
    if (lane == 0) {
        int best = 0;
        float bv = acc[0] + br[0];
#pragma unroll
        for (int e = 1; e < EE; e++) {
            float v = acc[e] + br[e];
            if (v > bv) { bv = v; best = e; }   // strict > == first-max (jnp.argmax)
        }
        int pos = atomicAdd(&counts[best], 1);
        tlist[best * NT + pos] = token;
    }
}

// ---- gather x rows into expert-sorted order, fp32 -> bf16 ----
__global__ __launch_bounds__(256) void gather_kernel(const float* __restrict__ x,
                                                     const int* __restrict__ tlist,
                                                     const int* __restrict__ counts,
                                                     unsigned short* __restrict__ xg) {
    const int row = blockIdx.x * 4 + (threadIdx.x >> 6);
    const int lane = threadIdx.x & 63;
    int off[EE];
    int s = 0;
#pragma unroll
    for (int k = 0; k < EE; k++) { off[k] = s; s += counts[k]; }
    int e = 0;
#pragma unroll
    for (int k = 1; k < EE; k++)
        if (row >= off[k]) e = k;
    const int token = tlist[e * NT + row - off[e]];
    const float4* src = (const float4*)(x + (size_t)token * DD);
    ushort4* dst = (ushort4*)(xg + (size_t)row * DD);
#pragma unroll
    for (int it = 0; it < 4; it++) {
        float4 v = src[it * 64 + lane];
        ushort4 o;
        o.x = f2bf(v.x); o.y = f2bf(v.y); o.z = f2bf(v.z); o.w = f2bf(v.w);
        dst[it * 64 + lane] = o;
    }
}

// LDS invariant (both GEMMs): LDS[row][slot] = logical chunk slot^((row>>1)&3).
// A (bf16): fetch swizzled global chunk, write linear (global_load_lds).
// B (fp32): fetch linear global chunk, cvt in regs, ds_write to swizzled slot.
// Fragment reads at slot kq^((mrow>>1)&3): 2-way banks = free.

// ---- up GEMM: h = silu(xg @ Wup[e]^T + bup[e]); fp32 B staged in-kernel ----
__global__ __launch_bounds__(256) void up_gemm(const unsigned short* __restrict__ xg,
                                               const float* __restrict__ Wup,
                                               const float* __restrict__ bup,
                                               const int* __restrict__ counts,
                                               unsigned short* __restrict__ hbuf) {
    const int e = blockIdx.z;
    int off_e = 0, cnt;
    {
        int s = 0;
#pragma unroll
        for (int k = 0; k < EE; k++) { if (k == e) off_e = s; s += counts[k]; }
        cnt = counts[e];
    }
    const int m0 = blockIdx.y * 128;
    if (m0 >= cnt) return;
    const int n0 = blockIdx.x * 128;
    const int t = threadIdx.x;

    __shared__ unsigned short sA[128 * 32];
    __shared__ unsigned short sB[128 * 32];

    const int r0 = t >> 2;
    const int kc = t & 3;
    const int ksw = (r0 >> 1) & 3;
    const int kcA = kc ^ ksw;
    const int c1 = cnt - 1;
    int ra = m0 + r0;      if (ra > c1) ra = c1;
    int rb = m0 + 64 + r0; if (rb > c1) rb = c1;
    const unsigned short* gA0 = xg + (size_t)(off_e + ra) * DD + kcA * 8;
    const unsigned short* gA1 = xg + (size_t)(off_e + rb) * DD + kcA * 8;
    const float* gB0 = Wup + ((size_t)e * HH + n0 + r0) * DD + kc * 8;
    const float* gB1 = Wup + ((size_t)e * HH + n0 + 64 + r0) * DD + kc * 8;
    unsigned short* lA0 = sA + t * 8;
    unsigned short* lA1 = sA + (t + 256) * 8;
    unsigned short* lB0 = sB + (r0 * 4 + (kc ^ ksw)) * 8;
    unsigned short* lB1 = sB + ((r0 + 64) * 4 + (kc ^ ksw)) * 8;

    const int lane = t & 63;
    const int wm = ((t >> 6) & 1) * 64;
    const int wn = (t >> 7) * 64;
    const int mrow = lane & 15;
    const int kq = lane >> 4;
    const int slot = (kq ^ ((mrow >> 1) & 3)) * 8;

    f32x4 acc[4][4];
#pragma unroll
    for (int i = 0; i < 4; i++)
#pragma unroll
        for (int j = 0; j < 4; j++)
            acc[i][j] = (f32x4){0.f, 0.f, 0.f, 0.f};

    for (int kt = 0; kt < DD; kt += 32) {
        float4 b00 = *(const float4*)(gB0 + kt);
        float4 b01 = *(const float4*)(gB0 + kt + 4);
        float4 b10 = *(const float4*)(gB1 + kt);
        float4 b11 = *(const float4*)(gB1 + kt + 4);
        __syncthreads();
        gload_lds16(gA0 + kt, lA0);
        gload_lds16(gA1 + kt, lA1);
        pack_store8(lB0, b00, b01);
        pack_store8(lB1, b10, b11);
        __syncthreads();
        short8 a[4], b[4];
#pragma unroll
        for (int i = 0; i < 4; i++) {
            a[i] = *(const short8*)(sA + (wm + i * 16 + mrow) * 32 + slot);
            b[i] = *(const short8*)(sB + (wn + i * 16 + mrow) * 32 + slot);
        }
#pragma unroll
        for (int i = 0; i < 4; i++)
#pragma unroll
            for (int j = 0; j < 4; j++)
                acc[i][j] = __builtin_amdgcn_mfma_f32_16x16x32_bf16(a[i], b[j], acc[i][j], 0, 0, 0);
    }

    float bias[4];
#pragma unroll
    for (int j = 0; j < 4; j++) bias[j] = bup[e * HH + n0 + wn + j * 16 + mrow];
#pragma unroll
    for (int i = 0; i < 4; i++) {
#pragma unroll
        for (int r = 0; r < 4; r++) {
            int m = m0 + wm + i * 16 + kq * 4 + r;
            if (m < cnt) {
                unsigned short* hrow = hbuf + (size_t)(off_e + m) * HH + n0 + wn + mrow;
#pragma unroll
                for (int j = 0; j < 4; j++) {
                    float v = acc[i][j][r] + bias[j];
                    v = v / (1.f + __expf(-v));   // silu
                    hrow[j * 16] = f2bf(v);
                }
            }
        }
    }
}

// ---- down GEMM, split-K x2 -> contiguous fp32 partials (no atomics) ----
__global__ __launch_bounds__(256) void down_gemm(const unsigned short* __restrict__ hbuf,
                                                 const float* __restrict__ Wdown,
                                                 const int* __restrict__ counts,
                                                 float* __restrict__ part) {
    const int e = blockIdx.z >> 1;
    const int sp = blockIdx.z & 1;
    int off_e = 0, cnt;
    {
        int s = 0;
#pragma unroll
        for (int k = 0; k < EE; k++) { if (k == e) off_e = s; s += counts[k]; }
        cnt = counts[e];
    }
    const int m0 = blockIdx.y * 128;
    if (m0 >= cnt) return;
    const int n0 = blockIdx.x * 128;
    const int t = threadIdx.x;

    __shared__ unsigned short sA[128 * 32];
    __shared__ unsigned short sB[128 * 32];

    const int r0 = t >> 2;
    const int kc = t & 3;
    const int ksw = (r0 >> 1) & 3;
    const int kcA = kc ^ ksw;
    const int c1 = cnt - 1;
    int ra = m0 + r0;      if (ra > c1) ra = c1;
    int rb = m0 + 64 + r0; if (rb > c1) rb = c1;
    const unsigned short* gA0 = hbuf + (size_t)(off_e + ra) * HH + kcA * 8;
    const unsigned short* gA1 = hbuf + (size_t)(off_e + rb) * HH + kcA * 8;
    const float* gB0 = Wdown + ((size_t)e * DD + n0 + r0) * HH + kc * 8;
    const float* gB1 = Wdown + ((size_t)e * DD + n0 + 64 + r0) * HH + kc * 8;
    unsigned short* lA0 = sA + t * 8;
    unsigned short* lA1 = sA + (t + 256) * 8;
    unsigned short* lB0 = sB + (r0 * 4 + (kc ^ ksw)) * 8;
    unsigned short* lB1 = sB + ((r0 + 64) * 4 + (kc ^ ksw)) * 8;

    const int lane = t & 63;
    const int wm = ((t >> 6) & 1) * 64;
    const int wn = (t >> 7) * 64;
    const int mrow = lane & 15;
    const int kq = lane >> 4;
    const int slot = (kq ^ ((mrow >> 1) & 3)) * 8;

    f32x4 acc[4][4];
#pragma unroll
    for (int i = 0; i < 4; i++)
#pragma unroll
        for (int j = 0; j < 4; j++)
            acc[i][j] = (f32x4){0.f, 0.f, 0.f, 0.f};

    const int kbeg = sp * (HH / 2);
    const int kend = kbeg + (HH / 2);
    for (int kt = kbeg; kt < kend; kt += 32) {
        float4 b00 = *(const float4*)(gB0 + kt);
        float4 b01 = *(const float4*)(gB0 + kt + 4);
        float4 b10 = *(const float4*)(gB1 + kt);
        float4 b11 = *(const float4*)(gB1 + kt + 4);
        __syncthreads();
        gload_lds16(gA0 + kt, lA0);
        gload_lds16(gA1 + kt, lA1);
        pack_store8(lB0, b00, b01);
        pack_store8(lB1, b10, b11);
        __syncthreads();
        short8 a[4], b[4];
#pragma unroll
        for (int i = 0; i < 4; i++) {
            a[i] = *(const short8*)(sA + (wm + i * 16 + mrow) * 32 + slot);
            b[i] = *(const short8*)(sB + (wn + i * 16 + mrow) * 32 + slot);
        }
#pragma unroll
        for (int i = 0; i < 4; i++)
#pragma unroll
            for (int j = 0; j < 4; j++)
                acc[i][j] = __builtin_amdgcn_mfma_f32_16x16x32_bf16(a[i], b[j], acc[i][j], 0, 0, 0);
    }

    float* pbase = part + (size_t)sp * NT * DD;
#pragma unroll
    for (int i = 0; i < 4; i++) {
#pragma unroll
        for (int r = 0; r < 4; r++) {
            int m = m0 + wm + i * 16 + kq * 4 + r;
            if (m < cnt) {
                float* prow = pbase + (size_t)(off_e + m) * DD + n0 + wn + mrow;
#pragma unroll
                for (int j = 0; j < 4; j++)
                    prow[j * 16] = acc[i][j][r];
            }
        }
    }
}

// ---- reduce partials + bias, scatter to out[token] ----
__global__ __launch_bounds__(256) void reduce_kernel(const float* __restrict__ part,
                                                     const float* __restrict__ bdown,
                                                     const int* __restrict__ counts,
                                                     const int* __restrict__ tlist,
                                                     float* __restrict__ out) {
    const int row = blockIdx.x * 4 + (threadIdx.x >> 6);
    const int lane = threadIdx.x & 63;
    int off[EE];
    int s = 0;
#pragma unroll
    for (int k = 0; k < EE; k++) { off[k] = s; s += counts[k]; }
    int e = 0;
#pragma unroll
    for (int k = 1; k < EE; k++)
        if (row >= off[k]) e = k;
    const int token = tlist[e * NT + row - off[e]];
    const float4* p0 = (const float4*)(part + (size_t)row * DD);
    const float4* p1 = (const float4*)(part + (size_t)(NT + row) * DD);
    const float4* bd = (const float4*)(bdown + (size_t)e * DD);
    float4* o = (float4*)(out + (size_t)token * DD);
#pragma unroll
    for (int it = 0; it < 4; it++) {
        int c = it * 64 + lane;
        float4 a = p0[c], b = p1[c], g = bd[c];
        float4 v;
        v.x = a.x + b.x + g.x;
        v.y = a.y + b.y + g.y;
        v.z = a.z + b.z + g.z;
        v.w = a.w + b.w + g.w;
        o[c] = v;
    }
}

extern "C" void kernel_launch(void* const* d_in, const int* in_sizes, int n_in,
                              void* d_out, int out_size, void* d_ws, size_t ws_size,
                              hipStream_t stream) {
    const float* x     = (const float*)d_in[0];
    const float* Wr    = (const float*)d_in[1];
    const float* br    = (const float*)d_in[2];
    const float* Wup   = (const float*)d_in[3];
    const float* bup   = (const float*)d_in[4];
    const float* Wdown = (const float*)d_in[5];
    const float* bdown = (const float*)d_in[6];
    float* out = (float*)d_out;

    char* w = (char*)d_ws;
    int* counts  = (int*)w;                     w += 256;
    int* tlist   = (int*)w;                     w += (size_t)EE * NT * 4;
    unsigned short* xg   = (unsigned short*)w;  w += (size_t)NT * DD * 2;
    unsigned short* hbuf = (unsigned short*)w;  w += (size_t)NT * HH * 2;
    float* part = (float*)w;                    w += (size_t)2 * NT * DD * 4;

    hipMemsetAsync(counts, 0, EE * sizeof(int), stream);

    router_kernel<<<NT / 4, 256, 0, stream>>>(x, Wr, br, counts, tlist);
    gather_kernel<<<NT / 4, 256, 0, stream>>>(x, tlist, counts, xg);

    dim3 gu(HH / 128, NT / 128, EE);
    up_gemm<<<gu, 256, 0, stream>>>(xg, Wup, bup, counts, hbuf);
    dim3 gd(DD / 128, NT / 128, EE * 2);
    down_gemm<<<gd, 256, 0, stream>>>(hbuf, Wdown, counts, part);
    reduce_kernel<<<NT / 4, 256, 0, stream>>>(part, bdown, counts, tlist, out);
}